// Round 14
// baseline (66.742 us; speedup 1.0000x reference)
//
#include <hip/hip_runtime.h>
#include <cstdint>
#include <cstddef>

// LSTMCreature, seq_len=1, h0=c0=0:
//   per layer: g = x @ Wih(gate rows).T + (bih+bhh); h = sig(go)*tanh(sig(gi)*tanh(gg))
//   f-gate skipped (multiplies c0=0), W_hh unused (h0=0).
// R14: BIG TILES. All prior structures used BM=64-128/BN=16-32 tiles ->
// 100-220MB of A/W re-read traffic per layer that (per R12 FETCH) streams
// from HBM: ~20us/layer floor = the observed invariant. This round:
// BM=256 x BN=64 per block (8 waves), traffic 56MB/layer (4x cut).
// Operands stay frag-linear (R10 layout) -> LDS staging is linear-to-linear
// gld16 (no swizzle); ds_read at lane*16B. 2-phase dbuf, grid=256 (1/CU),
// launch_bounds(512,2) = 256 regs/wave >= ~170 live (no spill).

#define NROWS 16384
#define HSZ   256

typedef _Float16 half8  __attribute__((ext_vector_type(8)));
typedef _Float16 half4v __attribute__((ext_vector_type(4)));
typedef float    f32x4  __attribute__((ext_vector_type(4)));

__device__ __forceinline__ void gld16(const void* g, void* l) {
    __builtin_amdgcn_global_load_lds(
        (const __attribute__((address_space(1))) void*)g,
        (__attribute__((address_space(3))) void*)l, 16, 0, 0);
}

__device__ __forceinline__ float fsig(float x)  { return 1.f / (1.f + __expf(-x)); }
__device__ __forceinline__ float ftanh(float x) { float e = __expf(2.f * x); return 1.f - 2.f / (e + 1.f); }

__device__ __forceinline__ int gate_remap(int row) {   // 768-row id -> 1024-row src (gates i,g,o)
    int g8 = row >> 8;
    int gate = (g8 == 0) ? 0 : g8 + 1;
    return gate * 256 + (row & 255);
}

// ---------------- fused prep: everything -> frag-linear fp16 ----------------

#define PS0 262144            /* x: 16384*128/8 half8-groups */
#define PS1 (PS0 + 12288)     /* W0: 768*128/8 */
#define PS2 (PS1 + 24576)     /* W1: 768*256/8 */
#define PS3 (PS2 + 24576)     /* W2 */
#define PS4 (PS3 + 2304)      /* bsums */
#define PS5 (PS4 + 4096)      /* fcW: 64*256/4 */

__global__ __launch_bounds__(256)
void prep_all_kernel(const float* __restrict__ x,
                     const float* __restrict__ W0, const float* __restrict__ b0i, const float* __restrict__ b0h,
                     const float* __restrict__ W1, const float* __restrict__ b1i, const float* __restrict__ b1h,
                     const float* __restrict__ W2, const float* __restrict__ b2i, const float* __restrict__ b2h,
                     const float* __restrict__ fcW,
                     _Float16* __restrict__ xf,
                     _Float16* __restrict__ W0f, _Float16* __restrict__ W1f, _Float16* __restrict__ W2f,
                     float* __restrict__ bs0, float* __restrict__ bs1, float* __restrict__ bs2,
                     _Float16* __restrict__ fWh)
{
    const int gid = blockIdx.x * 256 + threadIdx.x;
    if (gid < PS0) {
        int row = gid >> 4, kg = gid & 15;            // kg: 8-elem k-group
        const float* s = x + (size_t)row * 128 + kg * 8;
        f32x4 v0 = *(const f32x4*)s, v1 = *(const f32x4*)(s + 4);
        half8 h;
#pragma unroll
        for (int j = 0; j < 4; ++j) { h[j] = (_Float16)v0[j]; h[4 + j] = (_Float16)v1[j]; }
        int lane = (row & 15) | ((kg & 3) << 4);
        size_t idx = (((size_t)(row >> 4) * 4 + (kg >> 2)) * 64 + lane) * 8;
        *(half8*)(xf + idx) = h;
    } else if (gid < PS3) {
        const float* W; _Float16* Wf; int j, K, r768, kg, NTw;
        if (gid < PS1)      { j = gid - PS0; K = 128; W = W0; Wf = W0f; r768 = j >> 4; kg = j & 15; NTw = 4; }
        else if (gid < PS2) { j = gid - PS1; K = 256; W = W1; Wf = W1f; r768 = j >> 5; kg = j & 31; NTw = 8; }
        else                { j = gid - PS2; K = 256; W = W2; Wf = W2f; r768 = j >> 5; kg = j & 31; NTw = 8; }
        int src = gate_remap(r768);
        const float* s = W + (size_t)src * K + kg * 8;
        f32x4 v0 = *(const f32x4*)s, v1 = *(const f32x4*)(s + 4);
        half8 h;
#pragma unroll
        for (int jj = 0; jj < 4; ++jj) { h[jj] = (_Float16)v0[jj]; h[4 + jj] = (_Float16)v1[jj]; }
        int lane = (r768 & 15) | ((kg & 3) << 4);
        size_t idx = (((size_t)(r768 >> 4) * NTw + (kg >> 2)) * 64 + lane) * 8;
        *(half8*)(Wf + idx) = h;
    } else if (gid < PS4) {
        int j = gid - PS3;
        int l = (j >= 1536) ? 2 : (j >= 768 ? 1 : 0);
        int r = j - l * 768;
        int src = gate_remap(r);
        const float* bi = (l == 0) ? b0i : (l == 1) ? b1i : b2i;
        const float* bh = (l == 0) ? b0h : (l == 1) ? b1h : b2h;
        float* bs       = (l == 0) ? bs0 : (l == 1) ? bs1 : bs2;
        bs[r] = bi[src] + bh[src];
    } else if (gid < PS5) {
        int j = gid - PS4;            // 0..4095: fcW 64x256 in f32x4 chunks (LINEAR)
        f32x4 v = ((const f32x4*)fcW)[j];
        half4v h;
#pragma unroll
        for (int jj = 0; jj < 4; ++jj) h[jj] = (_Float16)v[jj];
        ((half4v*)fWh)[j] = h;
    }
}

// ---------------- layer kernel: 256m x 64n block, 8 waves, LDS dbuf ----------------
// bid (0..255): xc=bid&7, q=bid>>3: bidn=q&3, mid=xc+8*(q>>2) (0..63).
// Block rows mid*256, cols bidn*64. Wave (wm=wave>>1, wn=wave&1): 64m x 32n x 3g.
// Per kt: stage A 16 frags (16KB) + W 12 frags (12KB) linear->linear gld16;
// wave reads 4 A frags + 6 W frags, 24 MFMA. Traffic/layer: A 4x8MB + W 64x0.375MB.

template<int K>
__global__ __launch_bounds__(512, 2)
void lstm_mfma_kernel(const _Float16* __restrict__ Af,   // frag-linear [ru][NT][64][8]
                      const _Float16* __restrict__ Wf,   // frag-linear [48][NT][64][8]
                      const float* __restrict__ bsum,    // [768] linear
                      _Float16* __restrict__ Of)         // frag-linear [ru][8][64][8]
{
    constexpr int NT = K / 32;
    __shared__ __align__(16) _Float16 sA[2][16 * 512];   // 16KB each
    __shared__ __align__(16) _Float16 sW[2][12 * 512];   // 12KB each

    const int t    = threadIdx.x;
    const int lane = t & 63;
    const int wave = t >> 6;        // 0..7
    const int wm   = wave >> 1;     // 0..3: m quarter (64 rows)
    const int wn   = wave & 1;      // 0..1: n half (32 cols)
    const int lrow = lane & 15;
    const int lkb  = lane >> 4;

    const int bid  = blockIdx.x;
    const int xc   = bid & 7, q = bid >> 3;
    const int bidn = q & 3;
    const int mid  = xc + ((q >> 2) << 3);   // 0..63; bid%8 == mid%8
    const size_t ruA = (size_t)mid * 16;

    auto stage = [&](int bi, int kt) {
#pragma unroll
        for (int i = 0; i < 2; ++i) {                 // A: 1024 x 16B chunks
            int idx = t + i * 512;
            int fa = idx >> 6, lc = idx & 63;
            gld16(Af + ((ruA + fa) * NT + kt) * 512 + lc * 8, &sA[bi][idx * 8]);
        }
        if (t < 384) {                                // W: 768 chunks (waves 0-5)
#pragma unroll
            for (int i = 0; i < 2; ++i) {
                int idx = t + i * 384;
                int wf = idx >> 6, lc = idx & 63;     // wf 0..11: g=wf>>2, fl=wf&3
                int g = wf >> 2, fl = wf & 3;
                gld16(Wf + ((size_t)(g * 16 + bidn * 4 + fl) * NT + kt) * 512 + lc * 8,
                      &sW[bi][idx * 8]);
            }
        }
    };

    f32x4 acc[3][2][4];
#pragma unroll
    for (int g = 0; g < 3; ++g)
#pragma unroll
        for (int j = 0; j < 2; ++j)
#pragma unroll
            for (int fm = 0; fm < 4; ++fm) acc[g][j][fm] = (f32x4)0.f;

    auto compute = [&](int bi) {
        half8 a[4];
#pragma unroll
        for (int fm = 0; fm < 4; ++fm)
            a[fm] = *(const half8*)(&sA[bi][(wm * 4 + fm) * 512 + lane * 8]);
        half8 w[3][2];
#pragma unroll
        for (int g = 0; g < 3; ++g)
#pragma unroll
            for (int j = 0; j < 2; ++j)
                w[g][j] = *(const half8*)(&sW[bi][(g * 4 + wn * 2 + j) * 512 + lane * 8]);
        __builtin_amdgcn_s_setprio(1);
#pragma unroll
        for (int g = 0; g < 3; ++g)
#pragma unroll
            for (int j = 0; j < 2; ++j)
#pragma unroll
                for (int fm = 0; fm < 4; ++fm)
                    acc[g][j][fm] = __builtin_amdgcn_mfma_f32_16x16x32_f16(w[g][j], a[fm], acc[g][j][fm], 0, 0, 0);
        __builtin_amdgcn_s_setprio(0);
    };

    stage(0, 0);
    __syncthreads();
    int cur = 0;
    for (int kt = 0; kt < NT; ++kt) {
        if (kt + 1 < NT) stage(cur ^ 1, kt + 1);   // issue next tile, overlaps compute
        compute(cur);
        __syncthreads();                           // drains staging + read-release
        cur ^= 1;
    }

    // epilogue: m = mid*256 + wm*64 + fm*16 + lrow ; n = nu*16 + lkb*4 + jj,
    // nu = bidn*4 + wn*2 + j. Frag-linear store (NT_out=8 consumer):
    //   kt_o=nu>>1; lane_o=lrow|(((nu&1)<<1|(lkb>>1))<<4); elem=(lkb&1)*4
#pragma unroll
    for (int j = 0; j < 2; ++j) {
        const int nu    = bidn * 4 + wn * 2 + j;
        const int nbase = nu * 16 + lkb * 4;
        const f32x4 bI = *(const f32x4*)(bsum + nbase);
        const f32x4 bG = *(const f32x4*)(bsum + 256 + nbase);
        const f32x4 bO = *(const f32x4*)(bsum + 512 + nbase);
        const int kt_o   = nu >> 1;
        const int lane_o = lrow | ((((nu & 1) << 1) | (lkb >> 1)) << 4);
        const int elem   = (lkb & 1) * 4;
#pragma unroll
        for (int fm = 0; fm < 4; ++fm) {
            half4v oh;
#pragma unroll
            for (int jj = 0; jj < 4; ++jj) {
                float gi = acc[0][j][fm][jj] + bI[jj];
                float gg = acc[1][j][fm][jj] + bG[jj];
                float go = acc[2][j][fm][jj] + bO[jj];
                float c2 = fsig(gi) * ftanh(gg);
                oh[jj] = (_Float16)(fsig(go) * ftanh(c2));
            }
            size_t idx = (((size_t)(mid * 16 + wm * 4 + fm) * 8 + kt_o) * 64 + lane_o) * 8 + elem;
            *(half4v*)(Of + idx) = oh;
        }
    }
}

// ---------------- FC (MFMA, frag-linear H reads) + fused tanh-softmax-normalize ----------------

__global__ __launch_bounds__(256)
void fc_softmax_kernel(const _Float16* __restrict__ Hf,
                       const _Float16* __restrict__ fWh,
                       const float* __restrict__ fcb, float* __restrict__ out)
{
    __shared__ __align__(16) _Float16 sWh[64 * 256];   // 32KB

    const int t    = threadIdx.x;
    const int lane = t & 63;
    const int wave = t >> 6;
    const int ln   = lane & 15;
    const int lkb  = lane >> 4;
    const int m0   = blockIdx.x * 64;
    const int ru   = blockIdx.x * 4 + wave;

    // stage fcW plane via gld16: linear dest + inverse-swizzled source
#pragma unroll
    for (int i = 0; i < 8; ++i) {
        int j = i * 256 + t;            // 0..2047
        int row = j >> 5, c = j & 31;
        int cs  = c ^ (row & 7);
        gld16(fWh + row * 256 + cs * 8, sWh + j * 8);
    }

    const _Float16* pH = Hf + ((size_t)ru * 8) * 512 + lane * 8;

    f32x4 acc[4];
#pragma unroll
    for (int nf = 0; nf < 4; ++nf) acc[nf] = (f32x4)0.f;

    __syncthreads();   // drains gld16 (vmcnt 0) + orders LDS

#pragma unroll
    for (int kt = 0; kt < 8; ++kt) {
        half8 ah = *(const half8*)(pH + (size_t)kt * 512);
        __builtin_amdgcn_s_setprio(1);
#pragma unroll
        for (int nf = 0; nf < 4; ++nf) {
            int wr  = nf * 16 + ln;
            int ch  = kt * 4 + lkb;
            int off = wr * 256 + ((ch ^ (wr & 7)) << 3);
            half8 wwh = *(const half8*)(&sWh[off]);
            acc[nf] = __builtin_amdgcn_mfma_f32_16x16x32_f16(ah, wwh, acc[nf], 0, 0, 0);
        }
        __builtin_amdgcn_s_setprio(0);
    }

    // ---- epilogue: bias + tanh-softmax-normalize over n (64) per row ----
    float fb[4];
#pragma unroll
    for (int nf = 0; nf < 4; ++nf) fb[nf] = fcb[nf * 16 + ln];

    float tt[4][4], aa[4][4];
#pragma unroll
    for (int nf = 0; nf < 4; ++nf)
#pragma unroll
        for (int r = 0; r < 4; ++r) {
            float o = acc[nf][r] + fb[nf];
            tt[nf][r] = ftanh(o);
            aa[nf][r] = fabsf(o);
        }

    float mx[4];
#pragma unroll
    for (int r = 0; r < 4; ++r)
        mx[r] = fmaxf(fmaxf(aa[0][r], aa[1][r]), fmaxf(aa[2][r], aa[3][r]));
#pragma unroll
    for (int ofs = 1; ofs < 16; ofs <<= 1)
#pragma unroll
        for (int r = 0; r < 4; ++r) mx[r] = fmaxf(mx[r], __shfl_xor(mx[r], ofs, 64));

    float ee[4][4], Z[4];
#pragma unroll
    for (int r = 0; r < 4; ++r) Z[r] = 0.f;
#pragma unroll
    for (int nf = 0; nf < 4; ++nf)
#pragma unroll
        for (int r = 0; r < 4; ++r) { ee[nf][r] = __expf(aa[nf][r] - mx[r]); Z[r] += ee[nf][r]; }
#pragma unroll
    for (int ofs = 1; ofs < 16; ofs <<= 1)
#pragma unroll
        for (int r = 0; r < 4; ++r) Z[r] += __shfl_xor(Z[r], ofs, 64);

    float w[4][4], S[4];
#pragma unroll
    for (int r = 0; r < 4; ++r) S[r] = 0.f;
#pragma unroll
    for (int nf = 0; nf < 4; ++nf)
#pragma unroll
        for (int r = 0; r < 4; ++r) { w[nf][r] = tt[nf][r] * ee[nf][r] / Z[r]; S[r] += fabsf(w[nf][r]); }
#pragma unroll
    for (int ofs = 1; ofs < 16; ofs <<= 1)
#pragma unroll
        for (int r = 0; r < 4; ++r) S[r] += __shfl_xor(S[r], ofs, 64);

#pragma unroll
    for (int r = 0; r < 4; ++r) {
        const float inv = 1.f / fmaxf(S[r], 1e-12f);
        const int m = m0 + wave * 16 + lkb * 4 + r;
#pragma unroll
        for (int nf = 0; nf < 4; ++nf)
            out[(size_t)m * 64 + nf * 16 + ln] = w[nf][r] * inv;
    }
}

// ---------------- launch ----------------

extern "C" void kernel_launch(void* const* d_in, const int* in_sizes, int n_in,
                              void* d_out, int out_size, void* d_ws, size_t ws_size,
                              hipStream_t stream) {
    const float* x    = (const float*)d_in[0];
    const float* Wih0 = (const float*)d_in[1];
    const float* bih0 = (const float*)d_in[3];
    const float* bhh0 = (const float*)d_in[4];
    const float* Wih1 = (const float*)d_in[5];
    const float* bih1 = (const float*)d_in[7];
    const float* bhh1 = (const float*)d_in[8];
    const float* Wih2 = (const float*)d_in[9];
    const float* bih2 = (const float*)d_in[11];
    const float* bhh2 = (const float*)d_in[12];
    const float* fcW  = (const float*)d_in[13];
    const float* fcb  = (const float*)d_in[14];

    char* ws = (char*)d_ws;
    _Float16* hA  = (_Float16*)(ws);                   // 8 MB frag-linear
    _Float16* hB  = (_Float16*)(ws + (8u  << 20));     // 8 MB frag-linear
    _Float16* xf  = (_Float16*)(ws + (16u << 20));     // 4 MB frag-linear
    _Float16* W0f = (_Float16*)(ws + (20u << 20));     // 192 KB
    _Float16* W1f = (_Float16*)(ws + (21u << 20));     // 384 KB
    _Float16* W2f = (_Float16*)(ws + (22u << 20));     // 384 KB
    _Float16* fWh = (_Float16*)(ws + (23u << 20));     // 32 KB linear
    float*    bs0 = (float*)(ws + (24u << 20));
    float*    bs1 = (float*)(ws + (24u << 20) + 4096);
    float*    bs2 = (float*)(ws + (24u << 20) + 8192);
    float*    outp = (float*)d_out;

    prep_all_kernel<<<dim3(PS5 / 256), dim3(256), 0, stream>>>(
        x, Wih0, bih0, bhh0, Wih1, bih1, bhh1, Wih2, bih2, bhh2, fcW,
        xf, W0f, W1f, W2f, bs0, bs1, bs2, fWh);

    lstm_mfma_kernel<128><<<dim3(256), dim3(512), 0, stream>>>(xf, W0f, bs0, hA);
    lstm_mfma_kernel<256><<<dim3(256), dim3(512), 0, stream>>>(hA, W1f, bs1, hB);
    lstm_mfma_kernel<256><<<dim3(256), dim3(512), 0, stream>>>(hB, W2f, bs2, hA);

    fc_softmax_kernel<<<dim3(256), dim3(256), 0, stream>>>(hA, fWh, fcb, outp);
}